// Round 2
// baseline (587.384 us; speedup 1.0000x reference)
//
#include <hip/hip_runtime.h>
#include <hip/hip_bf16.h>

typedef __attribute__((ext_vector_type(4))) float f32x4;
typedef __attribute__((ext_vector_type(8))) short bf16x8;

__device__ __forceinline__ unsigned short f2bf(float f) {
    return __bfloat16_as_ushort(__float2bfloat16(f));
}

typedef __attribute__((address_space(1))) const unsigned char* gas_ptr;
typedef __attribute__((address_space(3))) unsigned char* las_ptr;
__device__ __forceinline__ void gload16(const void* g, void* l) {
    __builtin_amdgcn_global_load_lds((gas_ptr)g, (las_ptr)l, 16, 0, 0);
}

// ---------------- LayerNorm: fp32 in -> bf16 out -------------------
__global__ __launch_bounds__(256) void ln_kernel(
    const float* __restrict__ x, const float* __restrict__ scale,
    const float* __restrict__ bias, unsigned short* __restrict__ out)
{
    int row = blockIdx.x;
    const float* xr = x + (size_t)row * 1024;
    int t = threadIdx.x;
    float4 v = ((const float4*)xr)[t];
    float s  = v.x + v.y + v.z + v.w;
    float ss = v.x*v.x + v.y*v.y + v.z*v.z + v.w*v.w;
    #pragma unroll
    for (int m = 32; m; m >>= 1) { s += __shfl_down(s, m); ss += __shfl_down(ss, m); }
    __shared__ float red[8];
    int wid = t >> 6;
    if ((t & 63) == 0) { red[wid*2] = s; red[wid*2+1] = ss; }
    __syncthreads();
    s  = red[0] + red[2] + red[4] + red[6];
    ss = red[1] + red[3] + red[5] + red[7];
    float mu  = s * (1.0f/1024.0f);
    float var = ss * (1.0f/1024.0f) - mu*mu;
    float inv = rsqrtf(var + 1e-6f);
    float4 sc = ((const float4*)scale)[t];
    float4 bi = ((const float4*)bias)[t];
    ushort4 o;
    o.x = f2bf((v.x - mu)*inv*sc.x + bi.x);
    o.y = f2bf((v.y - mu)*inv*sc.y + bi.y);
    o.z = f2bf((v.z - mu)*inv*sc.z + bi.z);
    o.w = f2bf((v.w - mu)*inv*sc.w + bi.w);
    ((ushort4*)(out + (size_t)row * 1024))[t] = o;
}

// ---------------- Weight transpose: fp32 [K][N] -> bf16 [N][K] -----
__global__ __launch_bounds__(256) void transpose_kernel(
    const float* __restrict__ W, unsigned short* __restrict__ Wt, int K, int N)
{
    __shared__ float tile[32][33];
    int n0 = blockIdx.x * 32, k0 = blockIdx.y * 32;
    int tx = threadIdx.x, ty = threadIdx.y;
    #pragma unroll
    for (int j = 0; j < 32; j += 8)
        tile[ty + j][tx] = W[(size_t)(k0 + ty + j) * N + n0 + tx];
    __syncthreads();
    #pragma unroll
    for (int j = 0; j < 32; j += 8)
        Wt[(size_t)(n0 + ty + j) * K + k0 + tx] = f2bf(tile[tx][ty + j]);
}

// ---------------- GEMM: C = A[M,K](bf16) @ Bt[N,K](bf16)^T + bias --
// EPI 1: fp32 out + residual.  EPI 2: gelu -> bf16 out.
// EPI 3: bf16 out; cols >= 2048 also scattered into vt[bh][d][s].
template<int EPI>
__global__ __launch_bounds__(256) void gemm_kernel(
    const unsigned short* __restrict__ A,
    const unsigned short* __restrict__ Bt,
    const float* __restrict__ bias,
    const float* __restrict__ res,
    void* __restrict__ out,
    unsigned short* __restrict__ vtout,
    int M, int N, int K)
{
    __shared__ unsigned short Al[128 * 64];
    __shared__ unsigned short Bl[128 * 64];
    int t = threadIdx.x;
    int wid = t >> 6, lane = t & 63;
    int wr = wid >> 1, wc = wid & 1;
    int l15 = lane & 15, lg = lane >> 4;
    int brow = blockIdx.y * 128, bcol = blockIdx.x * 128;
    f32x4 acc[4][4] = {};
    int srow = t >> 3;            // 0..31: row within a 32-row staging slab
    int scol = (t & 7) * 8;       // col offset (elements)
    const unsigned short* ga = A  + (size_t)(brow + srow) * K + scol;
    const unsigned short* gb = Bt + (size_t)(bcol + srow) * K + scol;
    char* la = (char*)Al + wid * 1024;
    char* lb = (char*)Bl + wid * 1024;

    for (int k0 = 0; k0 < K; k0 += 64) {
        __syncthreads();   // previous tile fully consumed before overwrite
        #pragma unroll
        for (int i = 0; i < 4; i++) {
            gload16(ga + k0 + (size_t)(i * 32) * K, la + i * 4096);
            gload16(gb + k0 + (size_t)(i * 32) * K, lb + i * 4096);
        }
        __syncthreads();   // drains vmcnt -> staged data visible
        #pragma unroll
        for (int kf = 0; kf < 2; kf++) {
            bf16x8 af[4], bfr[4];
            #pragma unroll
            for (int m = 0; m < 4; m++) af[m]  = *(const bf16x8*)&Al[(wr*64 + m*16 + l15)*64 + kf*32 + lg*8];
            #pragma unroll
            for (int n = 0; n < 4; n++) bfr[n] = *(const bf16x8*)&Bl[(wc*64 + n*16 + l15)*64 + kf*32 + lg*8];
            #pragma unroll
            for (int m = 0; m < 4; m++)
                #pragma unroll
                for (int n = 0; n < 4; n++)
                    acc[m][n] = __builtin_amdgcn_mfma_f32_16x16x32_bf16(af[m], bfr[n], acc[m][n], 0, 0, 0);
        }
    }

    #pragma unroll
    for (int m = 0; m < 4; m++) {
        #pragma unroll
        for (int n = 0; n < 4; n++) {
            int col = bcol + wc*64 + n*16 + l15;
            float bs = bias[col];
            #pragma unroll
            for (int r = 0; r < 4; r++) {
                int row = brow + wr*64 + m*16 + lg*4 + r;
                size_t idx = (size_t)row * N + col;
                float v = acc[m][n][r] + bs;
                if (EPI == 1) {
                    ((float*)out)[idx] = v + res[idx];
                } else if (EPI == 2) {
                    // gelu(v) = v * sigmoid(1.59577*(v+0.044715 v^3)) via exp2
                    float u = v + 0.044715f * v * v * v;
                    float e = __builtin_amdgcn_exp2f(-2.3022077f * u);
                    float g = v * __builtin_amdgcn_rcpf(1.0f + e);
                    ((unsigned short*)out)[idx] = f2bf(g);
                } else {
                    unsigned short bv = f2bf(v);
                    ((unsigned short*)out)[idx] = bv;
                    if (col >= 2048) {
                        int hd = col - 2048;
                        int b = row >> 11, s = row & 2047;
                        vtout[((size_t)((b << 4) + (hd >> 6)) * 64 + (hd & 63)) * 2048 + s] = bv;
                    }
                }
            }
        }
    }
}

// ---------------- Flash attention -------------------------------
// qkv: bf16 [B*S][3072]; col = t*1024 + h*64 + d (t=0:q,1:k,2:v)
// vt : bf16 [B*H][64][2048]  (V transposed, precomputed by qkv GEMM epilogue)
// ctx: bf16 [B*S][1024], col = h*64 + d
__global__ __launch_bounds__(256) void attn_kernel(
    const unsigned short* __restrict__ qkv, const unsigned short* __restrict__ vt,
    unsigned short* __restrict__ ctx)
{
    __shared__ unsigned short Kl[64][72];
    __shared__ unsigned short Vtl[64][72];
    __shared__ unsigned short Pl[4][32][72];

    int bh = blockIdx.y;
    int b = bh >> 4, h = bh & 15;
    int qt = blockIdx.x;
    int t = threadIdx.x, wid = t >> 6, lane = t & 63;
    int l15 = lane & 15, lg = lane >> 4;
    const size_t base = (size_t)b * 2048 * 3072 + (size_t)h * 64;
    const unsigned short* vbase = vt + (size_t)bh * 64 * 2048;

    // Q fragments (held whole loop)
    bf16x8 qf[2][2];
    int qr0 = qt * 128 + wid * 32;
    #pragma unroll
    for (int m = 0; m < 2; m++)
        #pragma unroll
        for (int kf = 0; kf < 2; kf++)
            qf[m][kf] = *(const bf16x8*)(qkv + base + (size_t)(qr0 + m*16 + l15) * 3072 + kf*32 + lg*8);

    f32x4 o[2][4] = {};
    float mrun[2][4], lrun[2][4];
    #pragma unroll
    for (int m = 0; m < 2; m++)
        #pragma unroll
        for (int r = 0; r < 4; r++) { mrun[m][r] = -1e30f; lrun[m][r] = 0.0f; }

    const float C = 0.125f * 1.44269504f;   // scale folded into log2 domain

    int skey = t >> 2;            // 0..63
    int sdg  = (t & 3) * 16;      // 0,16,32,48

    for (int kt = 0; kt < 32; kt++) {
        __syncthreads();
        int key0 = kt * 64;
        // stage K [key][dim] (vectorized)
        const unsigned short* kp = qkv + base + 1024 + (size_t)(key0 + skey) * 3072 + sdg;
        *(uint4*)&Kl[skey][sdg]     = *(const uint4*)kp;
        *(uint4*)&Kl[skey][sdg + 8] = *(const uint4*)(kp + 8);
        // stage Vt [dim][key] (vectorized, from precomputed vt)
        const unsigned short* vp = vbase + (size_t)skey * 2048 + key0 + sdg;
        *(uint4*)&Vtl[skey][sdg]     = *(const uint4*)vp;
        *(uint4*)&Vtl[skey][sdg + 8] = *(const uint4*)(vp + 8);
        __syncthreads();

        // S = Q K^T
        f32x4 sa[2][4] = {};
        #pragma unroll
        for (int kf = 0; kf < 2; kf++) {
            bf16x8 kfr[4];
            #pragma unroll
            for (int n = 0; n < 4; n++) kfr[n] = *(const bf16x8*)&Kl[n*16 + l15][kf*32 + lg*8];
            #pragma unroll
            for (int m = 0; m < 2; m++)
                #pragma unroll
                for (int n = 0; n < 4; n++)
                    sa[m][n] = __builtin_amdgcn_mfma_f32_16x16x32_bf16(qf[m][kf], kfr[n], sa[m][n], 0, 0, 0);
        }

        // online softmax, log2 domain, defer-max (THR = 8/ln2)
        #pragma unroll
        for (int m = 0; m < 2; m++) {
            float pm[4];
            #pragma unroll
            for (int r = 0; r < 4; r++) {
                float v = fmaxf(fmaxf(sa[m][0][r], sa[m][1][r]), fmaxf(sa[m][2][r], sa[m][3][r]));
                pm[r] = v * C;
            }
            #pragma unroll
            for (int msk = 1; msk < 16; msk <<= 1)
                #pragma unroll
                for (int r = 0; r < 4; r++) pm[r] = fmaxf(pm[r], __shfl_xor(pm[r], msk));
            int grow = 0;
            #pragma unroll
            for (int r = 0; r < 4; r++) grow |= (pm[r] > mrun[m][r] + 11.5416f);
            if (__any(grow)) {
                #pragma unroll
                for (int r = 0; r < 4; r++) {
                    float mn = fmaxf(mrun[m][r], pm[r]);
                    float corr = __builtin_amdgcn_exp2f(mrun[m][r] - mn);
                    mrun[m][r] = mn;
                    lrun[m][r] *= corr;
                    #pragma unroll
                    for (int n2 = 0; n2 < 4; n2++) o[m][n2][r] *= corr;
                }
            }
            float rs[4] = {0.f, 0.f, 0.f, 0.f};
            #pragma unroll
            for (int n = 0; n < 4; n++) {
                #pragma unroll
                for (int r = 0; r < 4; r++) {
                    float pv = __builtin_amdgcn_exp2f(sa[m][n][r] * C - mrun[m][r]);
                    rs[r] += pv;
                    Pl[wid][m*16 + lg*4 + r][n*16 + l15] = f2bf(pv);
                }
            }
            #pragma unroll
            for (int msk = 1; msk < 16; msk <<= 1)
                #pragma unroll
                for (int r = 0; r < 4; r++) rs[r] += __shfl_xor(rs[r], msk);
            #pragma unroll
            for (int r = 0; r < 4; r++) lrun[m][r] += rs[r];
        }

        // wait for this wave's Pl writes (cross-lane within wave)
        asm volatile("s_waitcnt lgkmcnt(0)" ::: "memory");
        __builtin_amdgcn_sched_barrier(0);

        // O += P V
        #pragma unroll
        for (int kf2 = 0; kf2 < 2; kf2++) {
            bf16x8 vf[4];
            #pragma unroll
            for (int n2 = 0; n2 < 4; n2++) vf[n2] = *(const bf16x8*)&Vtl[n2*16 + l15][kf2*32 + lg*8];
            #pragma unroll
            for (int m = 0; m < 2; m++) {
                bf16x8 pa = *(const bf16x8*)&Pl[wid][m*16 + l15][kf2*32 + lg*8];
                #pragma unroll
                for (int n2 = 0; n2 < 4; n2++)
                    o[m][n2] = __builtin_amdgcn_mfma_f32_16x16x32_bf16(pa, vf[n2], o[m][n2], 0, 0, 0);
            }
        }
    }

    // write ctx
    size_t cbase = (size_t)b * 2048 * 1024 + (size_t)h * 64;
    #pragma unroll
    for (int m = 0; m < 2; m++) {
        float rcp[4];
        #pragma unroll
        for (int r = 0; r < 4; r++) rcp[r] = __builtin_amdgcn_rcpf(lrun[m][r]);
        #pragma unroll
        for (int n2 = 0; n2 < 4; n2++)
            #pragma unroll
            for (int r = 0; r < 4; r++) {
                int qr = qr0 + m*16 + lg*4 + r;
                ctx[cbase + (size_t)qr * 1024 + n2*16 + l15] = f2bf(o[m][n2][r] * rcp[r]);
            }
    }
}

// ---------------- launch ----------------
extern "C" void kernel_launch(void* const* d_in, const int* in_sizes, int n_in,
                              void* d_out, int out_size, void* d_ws, size_t ws_size,
                              hipStream_t stream) {
    const float* x      = (const float*)d_in[0];
    const float* ln1_s  = (const float*)d_in[1];
    const float* ln1_b  = (const float*)d_in[2];
    const float* ln2_s  = (const float*)d_in[3];
    const float* ln2_b  = (const float*)d_in[4];
    const float* qkv_w  = (const float*)d_in[5];
    const float* qkv_b  = (const float*)d_in[6];
    const float* proj_w = (const float*)d_in[7];
    const float* proj_b = (const float*)d_in[8];
    const float* fc1_w  = (const float*)d_in[9];
    const float* fc1_b  = (const float*)d_in[10];
    const float* fc2_w  = (const float*)d_in[11];
    const float* fc2_b  = (const float*)d_in[12];
    float* out = (float*)d_out;

    char* ws = (char*)d_ws;
    // layout (bytes), regions reused across phases:
    //   vt   @0    (16MB bf16)   [live: step3-4]
    //   x1   @0    (32MB fp32)   [live: step6-11]   (vt dead by then)
    //   h    @32M  (16MB bf16)   [live: 2-3, 7-9]
    //   qkvb @48M  (48MB bf16)   [live: 3-4]
    //   gbuf @48M  (64MB bf16)   [live: 9-11]       (qkvb/ctxb dead by 9/6)
    //   ctxb @96M  (16MB bf16)   [live: 4-6]
    //   wT   @112M (8MB bf16)
    unsigned short* vtb  = (unsigned short*)(ws + 0);
    float*          x1   = (float*)(ws + 0);
    unsigned short* h    = (unsigned short*)(ws + (size_t)32 * 1024 * 1024);
    unsigned short* qkvb = (unsigned short*)(ws + (size_t)48 * 1024 * 1024);
    unsigned short* gbuf = (unsigned short*)(ws + (size_t)48 * 1024 * 1024);
    unsigned short* ctxb = (unsigned short*)(ws + (size_t)96 * 1024 * 1024);
    unsigned short* wT   = (unsigned short*)(ws + (size_t)112 * 1024 * 1024);

    dim3 tb(32, 8);

    // 1) qkv_w^T
    transpose_kernel<<<dim3(96, 32), tb, 0, stream>>>(qkv_w, wT, 1024, 3072);
    // 2) h = LN1(x)
    ln_kernel<<<8192, 256, 0, stream>>>(x, ln1_s, ln1_b, h);
    // 3) qkv = h @ qkv_w + b   (+ V^T scatter)
    gemm_kernel<3><<<dim3(24, 64), 256, 0, stream>>>(h, wT, qkv_b, nullptr, qkvb, vtb, 8192, 3072, 1024);
    // 4) attention
    attn_kernel<<<dim3(16, 64), 256, 0, stream>>>(qkvb, vtb, ctxb);
    // 5) proj_w^T
    transpose_kernel<<<dim3(32, 32), tb, 0, stream>>>(proj_w, wT, 1024, 1024);
    // 6) x1 = x + ctx @ proj_w + b
    gemm_kernel<1><<<dim3(8, 64), 256, 0, stream>>>(ctxb, wT, proj_b, x, x1, nullptr, 8192, 1024, 1024);
    // 7) h = LN2(x1)
    ln_kernel<<<8192, 256, 0, stream>>>(x1, ln2_s, ln2_b, h);
    // 8) fc1_w^T
    transpose_kernel<<<dim3(128, 32), tb, 0, stream>>>(fc1_w, wT, 1024, 4096);
    // 9) g = gelu(h @ fc1_w + b)
    gemm_kernel<2><<<dim3(32, 64), 256, 0, stream>>>(h, wT, fc1_b, nullptr, gbuf, nullptr, 8192, 4096, 1024);
    // 10) fc2_w^T
    transpose_kernel<<<dim3(32, 128), tb, 0, stream>>>(fc2_w, wT, 4096, 1024);
    // 11) out = x1 + g @ fc2_w + b
    gemm_kernel<1><<<dim3(8, 64), 256, 0, stream>>>(gbuf, wT, fc2_b, x1, out, nullptr, 8192, 1024, 4096);
}

// Round 4
// 471.528 us; speedup vs baseline: 1.2457x; 1.2457x over previous
//
#include <hip/hip_runtime.h>
#include <hip/hip_bf16.h>

typedef __attribute__((ext_vector_type(4))) float f32x4;
typedef __attribute__((ext_vector_type(16))) float f32x16;
typedef __attribute__((ext_vector_type(8))) short bf16x8;

__device__ __forceinline__ unsigned short f2bf(float f) {
    return __bfloat16_as_ushort(__float2bfloat16(f));
}

typedef __attribute__((address_space(1))) const unsigned char* gas_ptr;
typedef __attribute__((address_space(3))) unsigned char* las_ptr;
__device__ __forceinline__ void gload16(const void* g, void* l) {
    __builtin_amdgcn_global_load_lds((gas_ptr)g, (las_ptr)l, 16, 0, 0);
}

__device__ __forceinline__ unsigned cvt_pk_bf16(float lo, float hi) {
    unsigned r;
    asm("v_cvt_pk_bf16_f32 %0, %1, %2" : "=v"(r) : "v"(lo), "v"(hi));
    return r;
}

// Exchange: for lanes 0-31, a <- partner(lane+32)'s b;
//           for lanes 32-63, b <- partner(lane-32)'s a.  (b of lo / a of hi keep.)
// Explicit shfl implementation — no dependence on permlane32_swap semantics.
__device__ __forceinline__ void plswap(unsigned &a, unsigned &b) {
    unsigned sa = (unsigned)__shfl_xor((int)a, 32);
    unsigned sb = (unsigned)__shfl_xor((int)b, 32);
    bool lo = (threadIdx.x & 63) < 32;
    unsigned na = lo ? sb : a;
    unsigned nb = lo ? b : sa;
    a = na; b = nb;
}

// ---------------- LayerNorm: fp32 in -> bf16 out -------------------
__global__ __launch_bounds__(256) void ln_kernel(
    const float* __restrict__ x, const float* __restrict__ scale,
    const float* __restrict__ bias, unsigned short* __restrict__ out)
{
    int row = blockIdx.x;
    const float* xr = x + (size_t)row * 1024;
    int t = threadIdx.x;
    float4 v = ((const float4*)xr)[t];
    float s  = v.x + v.y + v.z + v.w;
    float ss = v.x*v.x + v.y*v.y + v.z*v.z + v.w*v.w;
    #pragma unroll
    for (int m = 32; m; m >>= 1) { s += __shfl_down(s, m); ss += __shfl_down(ss, m); }
    __shared__ float red[8];
    int wid = t >> 6;
    if ((t & 63) == 0) { red[wid*2] = s; red[wid*2+1] = ss; }
    __syncthreads();
    s  = red[0] + red[2] + red[4] + red[6];
    ss = red[1] + red[3] + red[5] + red[7];
    float mu  = s * (1.0f/1024.0f);
    float var = ss * (1.0f/1024.0f) - mu*mu;
    float inv = rsqrtf(var + 1e-6f);
    float4 sc = ((const float4*)scale)[t];
    float4 bi = ((const float4*)bias)[t];
    ushort4 o;
    o.x = f2bf((v.x - mu)*inv*sc.x + bi.x);
    o.y = f2bf((v.y - mu)*inv*sc.y + bi.y);
    o.z = f2bf((v.z - mu)*inv*sc.z + bi.z);
    o.w = f2bf((v.w - mu)*inv*sc.w + bi.w);
    ((ushort4*)(out + (size_t)row * 1024))[t] = o;
}

// ---------------- Weight transpose: fp32 [K][N] -> bf16 [N][K] -----
__global__ __launch_bounds__(256) void transpose_kernel(
    const float* __restrict__ W, unsigned short* __restrict__ Wt, int K, int N)
{
    __shared__ float tile[32][33];
    int n0 = blockIdx.x * 32, k0 = blockIdx.y * 32;
    int tx = threadIdx.x, ty = threadIdx.y;
    #pragma unroll
    for (int j = 0; j < 32; j += 8)
        tile[ty + j][tx] = W[(size_t)(k0 + ty + j) * N + n0 + tx];
    __syncthreads();
    #pragma unroll
    for (int j = 0; j < 32; j += 8)
        Wt[(size_t)(n0 + ty + j) * K + k0 + tx] = f2bf(tile[tx][ty + j]);
}

// ---------------- GEMM: C = A[M,K](bf16) @ Bt[N,K](bf16)^T + bias --
// EPI 1: fp32 out + residual.  EPI 2: gelu -> bf16 out.
// EPI 3: bf16 out; cols >= 2048 also scattered into vt[bh][d][s].
template<int EPI>
__global__ __launch_bounds__(256) void gemm_kernel(
    const unsigned short* __restrict__ A,
    const unsigned short* __restrict__ Bt,
    const float* __restrict__ bias,
    const float* __restrict__ res,
    void* __restrict__ out,
    unsigned short* __restrict__ vtout,
    int M, int N, int K)
{
    __shared__ unsigned short Al[128 * 64];
    __shared__ unsigned short Bl[128 * 64];
    int t = threadIdx.x;
    int wid = t >> 6, lane = t & 63;
    int wr = wid >> 1, wc = wid & 1;
    int l15 = lane & 15, lg = lane >> 4;
    int brow = blockIdx.y * 128, bcol = blockIdx.x * 128;
    f32x4 acc[4][4] = {};
    int srow = t >> 3;
    int scol = (t & 7) * 8;
    const unsigned short* ga = A  + (size_t)(brow + srow) * K + scol;
    const unsigned short* gb = Bt + (size_t)(bcol + srow) * K + scol;
    char* la = (char*)Al + wid * 1024;
    char* lb = (char*)Bl + wid * 1024;

    for (int k0 = 0; k0 < K; k0 += 64) {
        __syncthreads();
        #pragma unroll
        for (int i = 0; i < 4; i++) {
            gload16(ga + k0 + (size_t)(i * 32) * K, la + i * 4096);
            gload16(gb + k0 + (size_t)(i * 32) * K, lb + i * 4096);
        }
        __syncthreads();
        #pragma unroll
        for (int kf = 0; kf < 2; kf++) {
            bf16x8 af[4], bfr[4];
            #pragma unroll
            for (int m = 0; m < 4; m++) af[m]  = *(const bf16x8*)&Al[(wr*64 + m*16 + l15)*64 + kf*32 + lg*8];
            #pragma unroll
            for (int n = 0; n < 4; n++) bfr[n] = *(const bf16x8*)&Bl[(wc*64 + n*16 + l15)*64 + kf*32 + lg*8];
            #pragma unroll
            for (int m = 0; m < 4; m++)
                #pragma unroll
                for (int n = 0; n < 4; n++)
                    acc[m][n] = __builtin_amdgcn_mfma_f32_16x16x32_bf16(af[m], bfr[n], acc[m][n], 0, 0, 0);
        }
    }

    #pragma unroll
    for (int m = 0; m < 4; m++) {
        #pragma unroll
        for (int n = 0; n < 4; n++) {
            int col = bcol + wc*64 + n*16 + l15;
            float bs = bias[col];
            #pragma unroll
            for (int r = 0; r < 4; r++) {
                int row = brow + wr*64 + m*16 + lg*4 + r;
                size_t idx = (size_t)row * N + col;
                float v = acc[m][n][r] + bs;
                if (EPI == 1) {
                    ((float*)out)[idx] = v + res[idx];
                } else if (EPI == 2) {
                    float u = v + 0.044715f * v * v * v;
                    float e = __builtin_amdgcn_exp2f(-2.3022077f * u);
                    float g = v * __builtin_amdgcn_rcpf(1.0f + e);
                    ((unsigned short*)out)[idx] = f2bf(g);
                } else {
                    unsigned short bv = f2bf(v);
                    ((unsigned short*)out)[idx] = bv;
                    if (col >= 2048) {
                        int hd = col - 2048;
                        int b = row >> 11, s = row & 2047;
                        vtout[((size_t)((b << 4) + (hd >> 6)) * 64 + (hd & 63)) * 2048 + s] = bv;
                    }
                }
            }
        }
    }
}

// ---------------- Flash attention (8-warp, 32x32 swapped) ----------
// qkv: bf16 [B*S][3072]; col = t*1024 + h*64 + d
// vt : bf16 [B*H][64][2048] (V^T per head)
// ctx: bf16 [B*S][1024], col = h*64 + d
// Per warp: 32 q-rows. S^T = K.Q^T (keys=M, q=N) so each lane owns q=lane&31.
// PV as O^T = V^T.P^T. P^T B-frags built in-register via cvt_pk + shfl exchange.
__global__ __launch_bounds__(512, 2) void attn_kernel(
    const unsigned short* __restrict__ qkv, const unsigned short* __restrict__ vt,
    unsigned short* __restrict__ ctx)
{
    __shared__ unsigned short Kl[2][4096];   // [64 keys][64 d], XOR-swizzled rows
    __shared__ unsigned short Vl[2][4096];   // [64 d][64 keys], XOR-swizzled rows

    int t = threadIdx.x;
    int wid = t >> 6, lane = t & 63;
    int l31 = lane & 31, half = lane >> 5;
    int bh = blockIdx.y;
    int b = bh >> 4, h = bh & 15;
    int qr0 = blockIdx.x * 256 + wid * 32;

    const size_t qbase = (size_t)b * 2048 * 3072 + (size_t)h * 64;
    const unsigned short* vbase = vt + (size_t)bh * 64 * 2048;

    // Q B-frags: lane holds Q[q=l31][ds*16 + half*8 + j]
    bf16x8 qf[4];
    #pragma unroll
    for (int ds = 0; ds < 4; ds++)
        qf[ds] = *(const bf16x8*)(qkv + qbase + (size_t)(qr0 + l31) * 3072 + ds*16 + half*8);

    f32x16 ot0 = {}, ot1 = {};
    float mrun = -1e30f, lrun = 0.0f;
    const float C = 0.125f * 1.44269504f;

    // staging: thread t covers LDS bytes [t*16, t*16+16) = row (t>>3), byte col (t&7)*16.
    // LDS stores row r with col c at c ^ ((r&7)<<4)  => load source col pre-swizzled.
    int srow = t >> 3;
    int ssw = ((t & 7) * 16) ^ ((srow & 7) << 4);
    const unsigned short* kg = qkv + qbase + 1024 + (size_t)srow * 3072 + (ssw >> 1);
    const unsigned short* vg = vbase + (size_t)srow * 2048 + (ssw >> 1);

    gload16(kg, (char*)Kl[0] + t * 16);
    gload16(vg, (char*)Vl[0] + t * 16);
    __syncthreads();

    int cur = 0;
    for (int kt = 0; kt < 32; kt++) {
        if (kt < 31) {
            gload16(kg + (size_t)(kt + 1) * 64 * 3072, (char*)Kl[cur ^ 1] + t * 16);
            gload16(vg + (kt + 1) * 64,               (char*)Vl[cur ^ 1] + t * 16);
        }

        const char* Kb = (const char*)Kl[cur];
        const char* Vb = (const char*)Vl[cur];

        // S^T = K . Q^T
        f32x16 st0 = {}, st1 = {};
        __builtin_amdgcn_s_setprio(1);
        #pragma unroll
        for (int ds = 0; ds < 4; ds++) {
            int colb = ds*32 + half*16;
            int sw = (l31 & 7) << 4;
            bf16x8 k0 = *(const bf16x8*)(Kb + l31*128 + (colb ^ sw));
            bf16x8 k1 = *(const bf16x8*)(Kb + (32 + l31)*128 + (colb ^ sw));
            st0 = __builtin_amdgcn_mfma_f32_32x32x16_bf16(k0, qf[ds], st0, 0, 0, 0);
            st1 = __builtin_amdgcn_mfma_f32_32x32x16_bf16(k1, qf[ds], st1, 0, 0, 0);
        }
        __builtin_amdgcn_s_setprio(0);

        // row max over own 32 keys, then lane-pair exchange
        float mx = fmaxf(st0[0], st0[1]);
        #pragma unroll
        for (int r = 2; r < 16; r++) mx = fmaxf(mx, st0[r]);
        #pragma unroll
        for (int r = 0; r < 16; r++) mx = fmaxf(mx, st1[r]);
        mx = fmaxf(mx, __shfl_xor(mx, 32));
        float pm = mx * C;

        // defer-max (THR = 8/ln2)
        bool grow = pm > mrun + 11.5416f;
        if (__any(grow)) {
            float mn = fmaxf(mrun, pm);
            float corr = __builtin_amdgcn_exp2f(mrun - mn);
            mrun = mn;
            lrun *= corr;
            ot0 *= corr;
            ot1 *= corr;
        }

        // P = exp2(S*C - mrun); pack to bf16 P^T B-frags in-register
        unsigned w0[8], w1[8];
        float sum = 0.0f;
        {
            float e[16];
            #pragma unroll
            for (int r = 0; r < 16; r++) { e[r] = __builtin_amdgcn_exp2f(fmaf(st0[r], C, -mrun)); sum += e[r]; }
            #pragma unroll
            for (int p = 0; p < 8; p++) w0[p] = cvt_pk_bf16(e[2*p], e[2*p+1]);
            #pragma unroll
            for (int r = 0; r < 16; r++) { e[r] = __builtin_amdgcn_exp2f(fmaf(st1[r], C, -mrun)); sum += e[r]; }
            #pragma unroll
            for (int p = 0; p < 8; p++) w1[p] = cvt_pk_bf16(e[2*p], e[2*p+1]);
        }
        lrun += sum;
        plswap(w0[2], w0[0]); plswap(w0[3], w0[1]);
        plswap(w0[6], w0[4]); plswap(w0[7], w0[5]);
        plswap(w1[2], w1[0]); plswap(w1[3], w1[1]);
        plswap(w1[6], w1[4]); plswap(w1[7], w1[5]);

        // O^T += V^T . P^T   (4 ksteps of 16 keys)
        __builtin_amdgcn_s_setprio(1);
        #pragma unroll
        for (int ks = 0; ks < 4; ks++) {
            union { unsigned u[4]; bf16x8 v; } pf;
            unsigned* w = (ks < 2) ? w0 : w1;
            int o4 = (ks & 1) * 4;
            pf.u[0] = w[o4 + 0]; pf.u[1] = w[o4 + 1]; pf.u[2] = w[o4 + 2]; pf.u[3] = w[o4 + 3];
            int colb = ks*32 + half*16;
            int sw = (l31 & 7) << 4;
            bf16x8 v0 = *(const bf16x8*)(Vb + l31*128 + (colb ^ sw));
            bf16x8 v1 = *(const bf16x8*)(Vb + (32 + l31)*128 + (colb ^ sw));
            ot0 = __builtin_amdgcn_mfma_f32_32x32x16_bf16(v0, pf.v, ot0, 0, 0, 0);
            ot1 = __builtin_amdgcn_mfma_f32_32x32x16_bf16(v1, pf.v, ot1, 0, 0, 0);
        }
        __builtin_amdgcn_s_setprio(0);

        __syncthreads();
        cur ^= 1;
    }

    // epilogue: combine lane-pair sums, normalize, write O[q][d]
    float ltot = lrun + __shfl_xor(lrun, 32);
    float rl = 1.0f / ltot;
    size_t cb = (size_t)b * 2048 * 1024 + (size_t)(qr0 + l31) * 1024 + (size_t)h * 64;
    #pragma unroll
    for (int r = 0; r < 16; r++) {
        int d = (r & 3) + 8 * (r >> 2) + 4 * half;
        ctx[cb + d]      = f2bf(ot0[r] * rl);
        ctx[cb + 32 + d] = f2bf(ot1[r] * rl);
    }
}

// ---------------- launch ----------------
extern "C" void kernel_launch(void* const* d_in, const int* in_sizes, int n_in,
                              void* d_out, int out_size, void* d_ws, size_t ws_size,
                              hipStream_t stream) {
    const float* x      = (const float*)d_in[0];
    const float* ln1_s  = (const float*)d_in[1];
    const float* ln1_b  = (const float*)d_in[2];
    const float* ln2_s  = (const float*)d_in[3];
    const float* ln2_b  = (const float*)d_in[4];
    const float* qkv_w  = (const float*)d_in[5];
    const float* qkv_b  = (const float*)d_in[6];
    const float* proj_w = (const float*)d_in[7];
    const float* proj_b = (const float*)d_in[8];
    const float* fc1_w  = (const float*)d_in[9];
    const float* fc1_b  = (const float*)d_in[10];
    const float* fc2_w  = (const float*)d_in[11];
    const float* fc2_b  = (const float*)d_in[12];
    float* out = (float*)d_out;

    char* ws = (char*)d_ws;
    unsigned short* vtb  = (unsigned short*)(ws + 0);
    float*          x1   = (float*)(ws + 0);
    unsigned short* h    = (unsigned short*)(ws + (size_t)32 * 1024 * 1024);
    unsigned short* qkvb = (unsigned short*)(ws + (size_t)48 * 1024 * 1024);
    unsigned short* gbuf = (unsigned short*)(ws + (size_t)48 * 1024 * 1024);
    unsigned short* ctxb = (unsigned short*)(ws + (size_t)96 * 1024 * 1024);
    unsigned short* wT   = (unsigned short*)(ws + (size_t)112 * 1024 * 1024);

    dim3 tb(32, 8);

    // 1) qkv_w^T
    transpose_kernel<<<dim3(96, 32), tb, 0, stream>>>(qkv_w, wT, 1024, 3072);
    // 2) h = LN1(x)
    ln_kernel<<<8192, 256, 0, stream>>>(x, ln1_s, ln1_b, h);
    // 3) qkv = h @ qkv_w + b   (+ V^T scatter)
    gemm_kernel<3><<<dim3(24, 64), 256, 0, stream>>>(h, wT, qkv_b, nullptr, qkvb, vtb, 8192, 3072, 1024);
    // 4) attention (8-warp 32x32)
    attn_kernel<<<dim3(8, 64), 512, 0, stream>>>(qkvb, vtb, ctxb);
    // 5) proj_w^T
    transpose_kernel<<<dim3(32, 32), tb, 0, stream>>>(proj_w, wT, 1024, 1024);
    // 6) x1 = x + ctx @ proj_w + b
    gemm_kernel<1><<<dim3(8, 64), 256, 0, stream>>>(ctxb, wT, proj_b, x, x1, nullptr, 8192, 1024, 1024);
    // 7) h = LN2(x1)
    ln_kernel<<<8192, 256, 0, stream>>>(x1, ln2_s, ln2_b, h);
    // 8) fc1_w^T
    transpose_kernel<<<dim3(128, 32), tb, 0, stream>>>(fc1_w, wT, 1024, 4096);
    // 9) g = gelu(h @ fc1_w + b)
    gemm_kernel<2><<<dim3(32, 64), 256, 0, stream>>>(h, wT, fc1_b, nullptr, gbuf, nullptr, 8192, 4096, 1024);
    // 10) fc2_w^T
    transpose_kernel<<<dim3(32, 128), tb, 0, stream>>>(fc2_w, wT, 4096, 1024);
    // 11) out = x1 + g @ fc2_w + b
    gemm_kernel<1><<<dim3(8, 64), 256, 0, stream>>>(gbuf, wT, fc2_b, x1, out, nullptr, 8192, 1024, 4096);
}

// Round 5
// 466.142 us; speedup vs baseline: 1.2601x; 1.0116x over previous
//
#include <hip/hip_runtime.h>
#include <hip/hip_bf16.h>

typedef __attribute__((ext_vector_type(4))) float f32x4;
typedef __attribute__((ext_vector_type(16))) float f32x16;
typedef __attribute__((ext_vector_type(8))) short bf16x8;

__device__ __forceinline__ unsigned short f2bf(float f) {
    return __bfloat16_as_ushort(__float2bfloat16(f));
}

typedef __attribute__((address_space(1))) const unsigned char* gas_ptr;
typedef __attribute__((address_space(3))) unsigned char* las_ptr;
__device__ __forceinline__ void gload16(const void* g, void* l) {
    __builtin_amdgcn_global_load_lds((gas_ptr)g, (las_ptr)l, 16, 0, 0);
}

__device__ __forceinline__ unsigned cvt_pk_bf16(float lo, float hi) {
    unsigned r;
    asm("v_cvt_pk_bf16_f32 %0, %1, %2" : "=v"(r) : "v"(lo), "v"(hi));
    return r;
}

// Exchange: for lanes 0-31, a <- partner(lane+32)'s b;
//           for lanes 32-63, b <- partner(lane-32)'s a.  (b of lo / a of hi keep.)
// Explicit shfl implementation — no dependence on permlane32_swap semantics.
__device__ __forceinline__ void plswap(unsigned &a, unsigned &b) {
    unsigned sa = (unsigned)__shfl_xor((int)a, 32);
    unsigned sb = (unsigned)__shfl_xor((int)b, 32);
    bool lo = (threadIdx.x & 63) < 32;
    unsigned na = lo ? sb : a;
    unsigned nb = lo ? b : sa;
    a = na; b = nb;
}

// ---------------- LayerNorm: fp32 in -> bf16 out -------------------
__global__ __launch_bounds__(256) void ln_kernel(
    const float* __restrict__ x, const float* __restrict__ scale,
    const float* __restrict__ bias, unsigned short* __restrict__ out)
{
    int row = blockIdx.x;
    const float* xr = x + (size_t)row * 1024;
    int t = threadIdx.x;
    float4 v = ((const float4*)xr)[t];
    float s  = v.x + v.y + v.z + v.w;
    float ss = v.x*v.x + v.y*v.y + v.z*v.z + v.w*v.w;
    #pragma unroll
    for (int m = 32; m; m >>= 1) { s += __shfl_down(s, m); ss += __shfl_down(ss, m); }
    __shared__ float red[8];
    int wid = t >> 6;
    if ((t & 63) == 0) { red[wid*2] = s; red[wid*2+1] = ss; }
    __syncthreads();
    s  = red[0] + red[2] + red[4] + red[6];
    ss = red[1] + red[3] + red[5] + red[7];
    float mu  = s * (1.0f/1024.0f);
    float var = ss * (1.0f/1024.0f) - mu*mu;
    float inv = rsqrtf(var + 1e-6f);
    float4 sc = ((const float4*)scale)[t];
    float4 bi = ((const float4*)bias)[t];
    ushort4 o;
    o.x = f2bf((v.x - mu)*inv*sc.x + bi.x);
    o.y = f2bf((v.y - mu)*inv*sc.y + bi.y);
    o.z = f2bf((v.z - mu)*inv*sc.z + bi.z);
    o.w = f2bf((v.w - mu)*inv*sc.w + bi.w);
    ((ushort4*)(out + (size_t)row * 1024))[t] = o;
}

// ---------------- Weight transpose: fp32 [K][N] -> bf16 [N][K] -----
__global__ __launch_bounds__(256) void transpose_kernel(
    const float* __restrict__ W, unsigned short* __restrict__ Wt, int K, int N)
{
    __shared__ float tile[32][33];
    int n0 = blockIdx.x * 32, k0 = blockIdx.y * 32;
    int tx = threadIdx.x, ty = threadIdx.y;
    #pragma unroll
    for (int j = 0; j < 32; j += 8)
        tile[ty + j][tx] = W[(size_t)(k0 + ty + j) * N + n0 + tx];
    __syncthreads();
    #pragma unroll
    for (int j = 0; j < 32; j += 8)
        Wt[(size_t)(n0 + ty + j) * K + k0 + tx] = f2bf(tile[tx][ty + j]);
}

// ---------------- GEMM: C = A[M,K](bf16) @ Bt[N,K](bf16)^T + bias --
// 2-phase double-buffered: stage kt+1 BEFORE computing kt; one barrier/iter.
// EPI 1: fp32 out + residual.  EPI 2: gelu -> bf16 out.
// EPI 3: bf16 out; cols >= 2048 also scattered into vt[bh][d][s].
template<int EPI>
__global__ __launch_bounds__(256) void gemm_kernel(
    const unsigned short* __restrict__ A,
    const unsigned short* __restrict__ Bt,
    const float* __restrict__ bias,
    const float* __restrict__ res,
    void* __restrict__ out,
    unsigned short* __restrict__ vtout,
    int M, int N, int K)
{
    __shared__ unsigned short Al[2][128 * 64];
    __shared__ unsigned short Bl[2][128 * 64];
    int t = threadIdx.x;
    int wid = t >> 6, lane = t & 63;
    int wr = wid >> 1, wc = wid & 1;
    int l15 = lane & 15, lg = lane >> 4;
    int brow = blockIdx.y * 128, bcol = blockIdx.x * 128;
    f32x4 acc[4][4] = {};
    int srow = t >> 3;            // 0..31: row within a 32-row staging slab
    int scol = (t & 7) * 8;       // col offset (elements)
    const unsigned short* ga = A  + (size_t)(brow + srow) * K + scol;
    const unsigned short* gb = Bt + (size_t)(bcol + srow) * K + scol;

    // prologue: stage K-tile 0 into buffer 0
    {
        char* la = (char*)Al[0] + wid * 1024;
        char* lb = (char*)Bl[0] + wid * 1024;
        #pragma unroll
        for (int i = 0; i < 4; i++) {
            gload16(ga + (size_t)(i * 32) * K, la + i * 4096);
            gload16(gb + (size_t)(i * 32) * K, lb + i * 4096);
        }
    }
    __syncthreads();   // drains vmcnt -> tile 0 visible

    int nk = K >> 6;
    for (int kt = 0; kt < nk; kt++) {
        int cur = kt & 1;
        // issue next tile's staging EARLY (lands in other buffer)
        if (kt + 1 < nk) {
            char* la = (char*)Al[cur ^ 1] + wid * 1024;
            char* lb = (char*)Bl[cur ^ 1] + wid * 1024;
            int k1 = (kt + 1) << 6;
            #pragma unroll
            for (int i = 0; i < 4; i++) {
                gload16(ga + k1 + (size_t)(i * 32) * K, la + i * 4096);
                gload16(gb + k1 + (size_t)(i * 32) * K, lb + i * 4096);
            }
        }
        // compute current tile (issue-to-wait distance = this whole region)
        const unsigned short* Ab = Al[cur];
        const unsigned short* Bb = Bl[cur];
        #pragma unroll
        for (int kf = 0; kf < 2; kf++) {
            bf16x8 af[4], bfr[4];
            #pragma unroll
            for (int m = 0; m < 4; m++) af[m]  = *(const bf16x8*)&Ab[(wr*64 + m*16 + l15)*64 + kf*32 + lg*8];
            #pragma unroll
            for (int n = 0; n < 4; n++) bfr[n] = *(const bf16x8*)&Bb[(wc*64 + n*16 + l15)*64 + kf*32 + lg*8];
            #pragma unroll
            for (int m = 0; m < 4; m++)
                #pragma unroll
                for (int n = 0; n < 4; n++)
                    acc[m][n] = __builtin_amdgcn_mfma_f32_16x16x32_bf16(af[m], bfr[n], acc[m][n], 0, 0, 0);
        }
        __syncthreads();   // single barrier/iter: drains own vmcnt + lgkm, syncs waves
    }

    #pragma unroll
    for (int m = 0; m < 4; m++) {
        #pragma unroll
        for (int n = 0; n < 4; n++) {
            int col = bcol + wc*64 + n*16 + l15;
            float bs = bias[col];
            #pragma unroll
            for (int r = 0; r < 4; r++) {
                int row = brow + wr*64 + m*16 + lg*4 + r;
                size_t idx = (size_t)row * N + col;
                float v = acc[m][n][r] + bs;
                if (EPI == 1) {
                    ((float*)out)[idx] = v + res[idx];
                } else if (EPI == 2) {
                    float u = v + 0.044715f * v * v * v;
                    float e = __builtin_amdgcn_exp2f(-2.3022077f * u);
                    float g = v * __builtin_amdgcn_rcpf(1.0f + e);
                    ((unsigned short*)out)[idx] = f2bf(g);
                } else {
                    unsigned short bv = f2bf(v);
                    ((unsigned short*)out)[idx] = bv;
                    if (col >= 2048) {
                        int hd = col - 2048;
                        int b = row >> 11, s = row & 2047;
                        vtout[((size_t)((b << 4) + (hd >> 6)) * 64 + (hd & 63)) * 2048 + s] = bv;
                    }
                }
            }
        }
    }
}

// ---------------- Flash attention (8-warp, 32x32 swapped) ----------
// qkv: bf16 [B*S][3072]; col = t*1024 + h*64 + d
// vt : bf16 [B*H][64][2048] (V^T per head)
// ctx: bf16 [B*S][1024], col = h*64 + d
// Per warp: 32 q-rows. S^T = K.Q^T (keys=M, q=N) so each lane owns q=lane&31.
// PV as O^T = V^T.P^T. P^T B-frags built in-register via cvt_pk + shfl exchange.
__global__ __launch_bounds__(512, 2) void attn_kernel(
    const unsigned short* __restrict__ qkv, const unsigned short* __restrict__ vt,
    unsigned short* __restrict__ ctx)
{
    __shared__ unsigned short Kl[2][4096];   // [64 keys][64 d], XOR-swizzled rows
    __shared__ unsigned short Vl[2][4096];   // [64 d][64 keys], XOR-swizzled rows

    int t = threadIdx.x;
    int wid = t >> 6, lane = t & 63;
    int l31 = lane & 31, half = lane >> 5;
    int bh = blockIdx.y;
    int b = bh >> 4, h = bh & 15;
    int qr0 = blockIdx.x * 256 + wid * 32;

    const size_t qbase = (size_t)b * 2048 * 3072 + (size_t)h * 64;
    const unsigned short* vbase = vt + (size_t)bh * 64 * 2048;

    // Q B-frags: lane holds Q[q=l31][ds*16 + half*8 + j]
    bf16x8 qf[4];
    #pragma unroll
    for (int ds = 0; ds < 4; ds++)
        qf[ds] = *(const bf16x8*)(qkv + qbase + (size_t)(qr0 + l31) * 3072 + ds*16 + half*8);

    f32x16 ot0 = {}, ot1 = {};
    float mrun = -1e30f, lrun = 0.0f;
    const float C = 0.125f * 1.44269504f;

    // staging: thread t covers LDS bytes [t*16, t*16+16) = row (t>>3), byte col (t&7)*16.
    // LDS stores row r with col c at c ^ ((r&7)<<4)  => load source col pre-swizzled.
    int srow = t >> 3;
    int ssw = ((t & 7) * 16) ^ ((srow & 7) << 4);
    const unsigned short* kg = qkv + qbase + 1024 + (size_t)srow * 3072 + (ssw >> 1);
    const unsigned short* vg = vbase + (size_t)srow * 2048 + (ssw >> 1);

    gload16(kg, (char*)Kl[0] + t * 16);
    gload16(vg, (char*)Vl[0] + t * 16);
    __syncthreads();

    int cur = 0;
    for (int kt = 0; kt < 32; kt++) {
        if (kt < 31) {
            gload16(kg + (size_t)(kt + 1) * 64 * 3072, (char*)Kl[cur ^ 1] + t * 16);
            gload16(vg + (kt + 1) * 64,               (char*)Vl[cur ^ 1] + t * 16);
        }

        const char* Kb = (const char*)Kl[cur];
        const char* Vb = (const char*)Vl[cur];

        // S^T = K . Q^T
        f32x16 st0 = {}, st1 = {};
        __builtin_amdgcn_s_setprio(1);
        #pragma unroll
        for (int ds = 0; ds < 4; ds++) {
            int colb = ds*32 + half*16;
            int sw = (l31 & 7) << 4;
            bf16x8 k0 = *(const bf16x8*)(Kb + l31*128 + (colb ^ sw));
            bf16x8 k1 = *(const bf16x8*)(Kb + (32 + l31)*128 + (colb ^ sw));
            st0 = __builtin_amdgcn_mfma_f32_32x32x16_bf16(k0, qf[ds], st0, 0, 0, 0);
            st1 = __builtin_amdgcn_mfma_f32_32x32x16_bf16(k1, qf[ds], st1, 0, 0, 0);
        }
        __builtin_amdgcn_s_setprio(0);

        // row max over own 32 keys, then lane-pair exchange
        float mx = fmaxf(st0[0], st0[1]);
        #pragma unroll
        for (int r = 2; r < 16; r++) mx = fmaxf(mx, st0[r]);
        #pragma unroll
        for (int r = 0; r < 16; r++) mx = fmaxf(mx, st1[r]);
        mx = fmaxf(mx, __shfl_xor(mx, 32));
        float pm = mx * C;

        // defer-max (THR = 8/ln2)
        bool grow = pm > mrun + 11.5416f;
        if (__any(grow)) {
            float mn = fmaxf(mrun, pm);
            float corr = __builtin_amdgcn_exp2f(mrun - mn);
            mrun = mn;
            lrun *= corr;
            ot0 *= corr;
            ot1 *= corr;
        }

        // P = exp2(S*C - mrun); pack to bf16 P^T B-frags in-register
        unsigned w0[8], w1[8];
        float sum = 0.0f;
        {
            float e[16];
            #pragma unroll
            for (int r = 0; r < 16; r++) { e[r] = __builtin_amdgcn_exp2f(fmaf(st0[r], C, -mrun)); sum += e[r]; }
            #pragma unroll
            for (int p = 0; p < 8; p++) w0[p] = cvt_pk_bf16(e[2*p], e[2*p+1]);
            #pragma unroll
            for (int r = 0; r < 16; r++) { e[r] = __builtin_amdgcn_exp2f(fmaf(st1[r], C, -mrun)); sum += e[r]; }
            #pragma unroll
            for (int p = 0; p < 8; p++) w1[p] = cvt_pk_bf16(e[2*p], e[2*p+1]);
        }
        lrun += sum;
        plswap(w0[2], w0[0]); plswap(w0[3], w0[1]);
        plswap(w0[6], w0[4]); plswap(w0[7], w0[5]);
        plswap(w1[2], w1[0]); plswap(w1[3], w1[1]);
        plswap(w1[6], w1[4]); plswap(w1[7], w1[5]);

        // O^T += V^T . P^T   (4 ksteps of 16 keys)
        __builtin_amdgcn_s_setprio(1);
        #pragma unroll
        for (int ks = 0; ks < 4; ks++) {
            union { unsigned u[4]; bf16x8 v; } pf;
            unsigned* w = (ks < 2) ? w0 : w1;
            int o4 = (ks & 1) * 4;
            pf.u[0] = w[o4 + 0]; pf.u[1] = w[o4 + 1]; pf.u[2] = w[o4 + 2]; pf.u[3] = w[o4 + 3];
            int colb = ks*32 + half*16;
            int sw = (l31 & 7) << 4;
            bf16x8 v0 = *(const bf16x8*)(Vb + l31*128 + (colb ^ sw));
            bf16x8 v1 = *(const bf16x8*)(Vb + (32 + l31)*128 + (colb ^ sw));
            ot0 = __builtin_amdgcn_mfma_f32_32x32x16_bf16(v0, pf.v, ot0, 0, 0, 0);
            ot1 = __builtin_amdgcn_mfma_f32_32x32x16_bf16(v1, pf.v, ot1, 0, 0, 0);
        }
        __builtin_amdgcn_s_setprio(0);

        __syncthreads();
        cur ^= 1;
    }

    // epilogue: combine lane-pair sums, normalize, write O[q][d]
    float ltot = lrun + __shfl_xor(lrun, 32);
    float rl = 1.0f / ltot;
    size_t cb = (size_t)b * 2048 * 1024 + (size_t)(qr0 + l31) * 1024 + (size_t)h * 64;
    #pragma unroll
    for (int r = 0; r < 16; r++) {
        int d = (r & 3) + 8 * (r >> 2) + 4 * half;
        ctx[cb + d]      = f2bf(ot0[r] * rl);
        ctx[cb + 32 + d] = f2bf(ot1[r] * rl);
    }
}

// ---------------- launch ----------------
extern "C" void kernel_launch(void* const* d_in, const int* in_sizes, int n_in,
                              void* d_out, int out_size, void* d_ws, size_t ws_size,
                              hipStream_t stream) {
    const float* x      = (const float*)d_in[0];
    const float* ln1_s  = (const float*)d_in[1];
    const float* ln1_b  = (const float*)d_in[2];
    const float* ln2_s  = (const float*)d_in[3];
    const float* ln2_b  = (const float*)d_in[4];
    const float* qkv_w  = (const float*)d_in[5];
    const float* qkv_b  = (const float*)d_in[6];
    const float* proj_w = (const float*)d_in[7];
    const float* proj_b = (const float*)d_in[8];
    const float* fc1_w  = (const float*)d_in[9];
    const float* fc1_b  = (const float*)d_in[10];
    const float* fc2_w  = (const float*)d_in[11];
    const float* fc2_b  = (const float*)d_in[12];
    float* out = (float*)d_out;

    char* ws = (char*)d_ws;
    unsigned short* vtb  = (unsigned short*)(ws + 0);
    float*          x1   = (float*)(ws + 0);
    unsigned short* h    = (unsigned short*)(ws + (size_t)32 * 1024 * 1024);
    unsigned short* qkvb = (unsigned short*)(ws + (size_t)48 * 1024 * 1024);
    unsigned short* gbuf = (unsigned short*)(ws + (size_t)48 * 1024 * 1024);
    unsigned short* ctxb = (unsigned short*)(ws + (size_t)96 * 1024 * 1024);
    unsigned short* wT   = (unsigned short*)(ws + (size_t)112 * 1024 * 1024);

    dim3 tb(32, 8);

    // 1) qkv_w^T
    transpose_kernel<<<dim3(96, 32), tb, 0, stream>>>(qkv_w, wT, 1024, 3072);
    // 2) h = LN1(x)
    ln_kernel<<<8192, 256, 0, stream>>>(x, ln1_s, ln1_b, h);
    // 3) qkv = h @ qkv_w + b   (+ V^T scatter)
    gemm_kernel<3><<<dim3(24, 64), 256, 0, stream>>>(h, wT, qkv_b, nullptr, qkvb, vtb, 8192, 3072, 1024);
    // 4) attention (8-warp 32x32)
    attn_kernel<<<dim3(8, 64), 512, 0, stream>>>(qkvb, vtb, ctxb);
    // 5) proj_w^T
    transpose_kernel<<<dim3(32, 32), tb, 0, stream>>>(proj_w, wT, 1024, 1024);
    // 6) x1 = x + ctx @ proj_w + b
    gemm_kernel<1><<<dim3(8, 64), 256, 0, stream>>>(ctxb, wT, proj_b, x, x1, nullptr, 8192, 1024, 1024);
    // 7) h = LN2(x1)
    ln_kernel<<<8192, 256, 0, stream>>>(x1, ln2_s, ln2_b, h);
    // 8) fc1_w^T
    transpose_kernel<<<dim3(128, 32), tb, 0, stream>>>(fc1_w, wT, 1024, 4096);
    // 9) g = gelu(h @ fc1_w + b)
    gemm_kernel<2><<<dim3(32, 64), 256, 0, stream>>>(h, wT, fc1_b, nullptr, gbuf, nullptr, 8192, 4096, 1024);
    // 10) fc2_w^T
    transpose_kernel<<<dim3(32, 128), tb, 0, stream>>>(fc2_w, wT, 4096, 1024);
    // 11) out = x1 + g @ fc2_w + b
    gemm_kernel<1><<<dim3(8, 64), 256, 0, stream>>>(gbuf, wT, fc2_b, x1, out, nullptr, 8192, 1024, 4096);
}

// Round 6
// 426.741 us; speedup vs baseline: 1.3764x; 1.0923x over previous
//
#include <hip/hip_runtime.h>
#include <hip/hip_bf16.h>

typedef __attribute__((ext_vector_type(4))) float f32x4;
typedef __attribute__((ext_vector_type(16))) float f32x16;
typedef __attribute__((ext_vector_type(8))) short bf16x8;

__device__ __forceinline__ unsigned short f2bf(float f) {
    return __bfloat16_as_ushort(__float2bfloat16(f));
}

typedef __attribute__((address_space(1))) const unsigned char* gas_ptr;
typedef __attribute__((address_space(3))) unsigned char* las_ptr;
__device__ __forceinline__ void gload16(const void* g, void* l) {
    __builtin_amdgcn_global_load_lds((gas_ptr)g, (las_ptr)l, 16, 0, 0);
}

__device__ __forceinline__ unsigned cvt_pk_bf16(float lo, float hi) {
    unsigned r;
    asm("v_cvt_pk_bf16_f32 %0, %1, %2" : "=v"(r) : "v"(lo), "v"(hi));
    return r;
}

// Exchange: lanes 0-31: a <- partner's b; lanes 32-63: b <- partner's a.
__device__ __forceinline__ void plswap(unsigned &a, unsigned &b) {
    unsigned sa = (unsigned)__shfl_xor((int)a, 32);
    unsigned sb = (unsigned)__shfl_xor((int)b, 32);
    bool lo = (threadIdx.x & 63) < 32;
    unsigned na = lo ? sb : a;
    unsigned nb = lo ? b : sa;
    a = na; b = nb;
}

// ---------------- LayerNorm: fp32 in -> bf16 out -------------------
__global__ __launch_bounds__(256) void ln_kernel(
    const float* __restrict__ x, const float* __restrict__ scale,
    const float* __restrict__ bias, unsigned short* __restrict__ out)
{
    int row = blockIdx.x;
    const float* xr = x + (size_t)row * 1024;
    int t = threadIdx.x;
    float4 v = ((const float4*)xr)[t];
    float s  = v.x + v.y + v.z + v.w;
    float ss = v.x*v.x + v.y*v.y + v.z*v.z + v.w*v.w;
    #pragma unroll
    for (int m = 32; m; m >>= 1) { s += __shfl_down(s, m); ss += __shfl_down(ss, m); }
    __shared__ float red[8];
    int wid = t >> 6;
    if ((t & 63) == 0) { red[wid*2] = s; red[wid*2+1] = ss; }
    __syncthreads();
    s  = red[0] + red[2] + red[4] + red[6];
    ss = red[1] + red[3] + red[5] + red[7];
    float mu  = s * (1.0f/1024.0f);
    float var = ss * (1.0f/1024.0f) - mu*mu;
    float inv = rsqrtf(var + 1e-6f);
    float4 sc = ((const float4*)scale)[t];
    float4 bi = ((const float4*)bias)[t];
    ushort4 o;
    o.x = f2bf((v.x - mu)*inv*sc.x + bi.x);
    o.y = f2bf((v.y - mu)*inv*sc.y + bi.y);
    o.z = f2bf((v.z - mu)*inv*sc.z + bi.z);
    o.w = f2bf((v.w - mu)*inv*sc.w + bi.w);
    ((ushort4*)(out + (size_t)row * 1024))[t] = o;
}

// ---------------- Weight transpose: fp32 [K][N] -> bf16 [N][K] -----
__global__ __launch_bounds__(256) void transpose_kernel(
    const float* __restrict__ W, unsigned short* __restrict__ Wt, int K, int N)
{
    __shared__ float tile[32][33];
    int n0 = blockIdx.x * 32, k0 = blockIdx.y * 32;
    int tx = threadIdx.x, ty = threadIdx.y;
    #pragma unroll
    for (int j = 0; j < 32; j += 8)
        tile[ty + j][tx] = W[(size_t)(k0 + ty + j) * N + n0 + tx];
    __syncthreads();
    #pragma unroll
    for (int j = 0; j < 32; j += 8)
        Wt[(size_t)(n0 + ty + j) * K + k0 + tx] = f2bf(tile[tx][ty + j]);
}

// ------- GEMM 256xBN tile, swizzled LDS, raw-barrier dbuf ---------
// C = A[M,K](bf16) @ Bt[N,K](bf16)^T + bias
// EPI 1: fp32 out + residual.  EPI 2: gelu -> bf16.  EPI 3: bf16 + V^T scatter.
// LDS rows are 64 bf16 = 128 B; data at lds[r][cbyte] = global (r, cbyte ^ ((r&7)<<4)).
template<int EPI, int BN>
__global__ __launch_bounds__(512, 2) void gemm256_kernel(
    const unsigned short* __restrict__ A,
    const unsigned short* __restrict__ Bt,
    const float* __restrict__ bias,
    const float* __restrict__ res,
    void* __restrict__ out,
    unsigned short* __restrict__ vtout,
    int M, int N, int K)
{
    constexpr int BM = 256;
    constexpr int WARPS_N = (BN == 256) ? 4 : 2;
    constexpr int WM = (BN == 256) ? 128 : 64;   // wave M-span
    constexpr int WN = 64;                        // wave N-span
    constexpr int MQ = WM / 64;                   // m-quads per wave (2 or 1)
    constexpr int NF = WN / 16;                   // 4 n-frags
    constexpr int NB = BN / 64;                   // B staging batches (4 or 2)

    __shared__ __align__(16) unsigned short Al[2][BM * 64];
    __shared__ __align__(16) unsigned short Bl[2][BN * 64];

    int t = threadIdx.x;
    int wid = t >> 6, lane = t & 63;
    int wr = wid / WARPS_N, wc = wid % WARPS_N;
    int l15 = lane & 15, lg = lane >> 4;

    // XCD-aware bijective block swizzle (all grids divisible by 8)
    int gx = gridDim.x;
    int nwg = gx * gridDim.y;
    int orig = blockIdx.y * gx + blockIdx.x;
    int cpx = nwg >> 3;
    int wg = (orig & 7) * cpx + (orig >> 3);
    int bx = wg % gx, by = wg / gx;
    int brow = by * BM, bcol = bx * BN;

    f32x4 acc[MQ * 4][NF] = {};

    // staging geometry: thread t covers LDS linear bytes t*16 of each 8 KB slab
    int sr  = t >> 3;                       // 0..63 row within slab
    int scb = (t & 7) * 16;                 // byte col
    int sce = (scb ^ ((sr & 7) << 4)) >> 1; // pre-swizzled source col (elements)
    const size_t aoff = (size_t)(brow + sr) * K + sce;
    const size_t boff = (size_t)(bcol + sr) * K + sce;

    auto stage = [&](int b, int kt2) {
        int k0 = kt2 << 6;
        char* la = (char*)Al[b] + (wid << 10);
        char* lb = (char*)Bl[b] + (wid << 10);
        #pragma unroll
        for (int i = 0; i < 4; i++)
            gload16(A + aoff + (size_t)(i * 64) * K + k0, la + i * 8192);
        #pragma unroll
        for (int j = 0; j < NB; j++)
            gload16(Bt + boff + (size_t)(j * 64) * K + k0, lb + j * 8192);
    };

    stage(0, 0);
    asm volatile("s_waitcnt vmcnt(0)" ::: "memory");
    __builtin_amdgcn_s_barrier();

    int nk = K >> 6;
    int rsw = (l15 & 7) << 4;
    for (int kt = 0; kt < nk; kt++) {
        int cur = kt & 1;
        if (kt + 1 < nk) stage(cur ^ 1, kt + 1);

        const char* Ab = (const char*)Al[cur];
        const char* Bb = (const char*)Bl[cur];

        bf16x8 bfr[NF][2];
        #pragma unroll
        for (int nf = 0; nf < NF; nf++) {
            int rb = wc * WN + nf * 16 + l15;
            #pragma unroll
            for (int kk = 0; kk < 2; kk++)
                bfr[nf][kk] = *(const bf16x8*)(Bb + rb * 128 + ((kk * 64 + lg * 16) ^ rsw));
        }
        #pragma unroll
        for (int mq = 0; mq < MQ; mq++) {
            bf16x8 af[4][2];
            #pragma unroll
            for (int mf = 0; mf < 4; mf++) {
                int ra = wr * WM + mq * 64 + mf * 16 + l15;
                #pragma unroll
                for (int kk = 0; kk < 2; kk++)
                    af[mf][kk] = *(const bf16x8*)(Ab + ra * 128 + ((kk * 64 + lg * 16) ^ rsw));
            }
            __builtin_amdgcn_s_setprio(1);
            #pragma unroll
            for (int mf = 0; mf < 4; mf++)
                #pragma unroll
                for (int nf = 0; nf < NF; nf++)
                    #pragma unroll
                    for (int kk = 0; kk < 2; kk++)
                        acc[mq*4+mf][nf] = __builtin_amdgcn_mfma_f32_16x16x32_bf16(
                            af[mf][kk], bfr[nf][kk], acc[mq*4+mf][nf], 0, 0, 0);
            __builtin_amdgcn_s_setprio(0);
        }

        asm volatile("s_waitcnt vmcnt(0)" ::: "memory");
        __builtin_amdgcn_s_barrier();
    }

    // epilogue
    #pragma unroll
    for (int mi = 0; mi < MQ * 4; mi++) {
        #pragma unroll
        for (int nf = 0; nf < NF; nf++) {
            int col = bcol + wc * WN + nf * 16 + l15;
            float bs = bias[col];
            #pragma unroll
            for (int r = 0; r < 4; r++) {
                int row = brow + wr * WM + mi * 16 + lg * 4 + r;
                size_t idx = (size_t)row * N + col;
                float v = acc[mi][nf][r] + bs;
                if (EPI == 1) {
                    ((float*)out)[idx] = v + res[idx];
                } else if (EPI == 2) {
                    float u = v + 0.044715f * v * v * v;
                    float e = __builtin_amdgcn_exp2f(-2.3022077f * u);
                    float g = v * __builtin_amdgcn_rcpf(1.0f + e);
                    ((unsigned short*)out)[idx] = f2bf(g);
                } else {
                    unsigned short bv = f2bf(v);
                    ((unsigned short*)out)[idx] = bv;
                    if (col >= 2048) {
                        int hd = col - 2048;
                        int b = row >> 11, s = row & 2047;
                        vtout[((size_t)((b << 4) + (hd >> 6)) * 64 + (hd & 63)) * 2048 + s] = bv;
                    }
                }
            }
        }
    }
}

// ---------------- Flash attention (8-warp, 32x32 swapped) ----------
__global__ __launch_bounds__(512, 2) void attn_kernel(
    const unsigned short* __restrict__ qkv, const unsigned short* __restrict__ vt,
    unsigned short* __restrict__ ctx)
{
    __shared__ unsigned short Kl[2][4096];   // [64 keys][64 d], XOR-swizzled rows
    __shared__ unsigned short Vl[2][4096];   // [64 d][64 keys], XOR-swizzled rows

    int t = threadIdx.x;
    int wid = t >> 6, lane = t & 63;
    int l31 = lane & 31, half = lane >> 5;
    int bh = blockIdx.y;
    int b = bh >> 4, h = bh & 15;
    int qr0 = blockIdx.x * 256 + wid * 32;

    const size_t qbase = (size_t)b * 2048 * 3072 + (size_t)h * 64;
    const unsigned short* vbase = vt + (size_t)bh * 64 * 2048;

    bf16x8 qf[4];
    #pragma unroll
    for (int ds = 0; ds < 4; ds++)
        qf[ds] = *(const bf16x8*)(qkv + qbase + (size_t)(qr0 + l31) * 3072 + ds*16 + half*8);

    f32x16 ot0 = {}, ot1 = {};
    float mrun = -1e30f, lrun = 0.0f;
    const float C = 0.125f * 1.44269504f;

    int srow = t >> 3;
    int ssw = ((t & 7) * 16) ^ ((srow & 7) << 4);
    const unsigned short* kg = qkv + qbase + 1024 + (size_t)srow * 3072 + (ssw >> 1);
    const unsigned short* vg = vbase + (size_t)srow * 2048 + (ssw >> 1);

    gload16(kg, (char*)Kl[0] + t * 16);
    gload16(vg, (char*)Vl[0] + t * 16);
    __syncthreads();

    int cur = 0;
    for (int kt = 0; kt < 32; kt++) {
        if (kt < 31) {
            gload16(kg + (size_t)(kt + 1) * 64 * 3072, (char*)Kl[cur ^ 1] + t * 16);
            gload16(vg + (kt + 1) * 64,               (char*)Vl[cur ^ 1] + t * 16);
        }

        const char* Kb = (const char*)Kl[cur];
        const char* Vb = (const char*)Vl[cur];

        f32x16 st0 = {}, st1 = {};
        __builtin_amdgcn_s_setprio(1);
        #pragma unroll
        for (int ds = 0; ds < 4; ds++) {
            int colb = ds*32 + half*16;
            int sw = (l31 & 7) << 4;
            bf16x8 k0 = *(const bf16x8*)(Kb + l31*128 + (colb ^ sw));
            bf16x8 k1 = *(const bf16x8*)(Kb + (32 + l31)*128 + (colb ^ sw));
            st0 = __builtin_amdgcn_mfma_f32_32x32x16_bf16(k0, qf[ds], st0, 0, 0, 0);
            st1 = __builtin_amdgcn_mfma_f32_32x32x16_bf16(k1, qf[ds], st1, 0, 0, 0);
        }
        __builtin_amdgcn_s_setprio(0);

        float mx = fmaxf(st0[0], st0[1]);
        #pragma unroll
        for (int r = 2; r < 16; r++) mx = fmaxf(mx, st0[r]);
        #pragma unroll
        for (int r = 0; r < 16; r++) mx = fmaxf(mx, st1[r]);
        mx = fmaxf(mx, __shfl_xor(mx, 32));
        float pm = mx * C;

        bool grow = pm > mrun + 11.5416f;
        if (__any(grow)) {
            float mn = fmaxf(mrun, pm);
            float corr = __builtin_amdgcn_exp2f(mrun - mn);
            mrun = mn;
            lrun *= corr;
            ot0 *= corr;
            ot1 *= corr;
        }

        unsigned w0[8], w1[8];
        float sum = 0.0f;
        {
            float e[16];
            #pragma unroll
            for (int r = 0; r < 16; r++) { e[r] = __builtin_amdgcn_exp2f(fmaf(st0[r], C, -mrun)); sum += e[r]; }
            #pragma unroll
            for (int p = 0; p < 8; p++) w0[p] = cvt_pk_bf16(e[2*p], e[2*p+1]);
            #pragma unroll
            for (int r = 0; r < 16; r++) { e[r] = __builtin_amdgcn_exp2f(fmaf(st1[r], C, -mrun)); sum += e[r]; }
            #pragma unroll
            for (int p = 0; p < 8; p++) w1[p] = cvt_pk_bf16(e[2*p], e[2*p+1]);
        }
        lrun += sum;
        plswap(w0[2], w0[0]); plswap(w0[3], w0[1]);
        plswap(w0[6], w0[4]); plswap(w0[7], w0[5]);
        plswap(w1[2], w1[0]); plswap(w1[3], w1[1]);
        plswap(w1[6], w1[4]); plswap(w1[7], w1[5]);

        __builtin_amdgcn_s_setprio(1);
        #pragma unroll
        for (int ks = 0; ks < 4; ks++) {
            union { unsigned u[4]; bf16x8 v; } pf;
            unsigned* w = (ks < 2) ? w0 : w1;
            int o4 = (ks & 1) * 4;
            pf.u[0] = w[o4 + 0]; pf.u[1] = w[o4 + 1]; pf.u[2] = w[o4 + 2]; pf.u[3] = w[o4 + 3];
            int colb = ks*32 + half*16;
            int sw = (l31 & 7) << 4;
            bf16x8 v0 = *(const bf16x8*)(Vb + l31*128 + (colb ^ sw));
            bf16x8 v1 = *(const bf16x8*)(Vb + (32 + l31)*128 + (colb ^ sw));
            ot0 = __builtin_amdgcn_mfma_f32_32x32x16_bf16(v0, pf.v, ot0, 0, 0, 0);
            ot1 = __builtin_amdgcn_mfma_f32_32x32x16_bf16(v1, pf.v, ot1, 0, 0, 0);
        }
        __builtin_amdgcn_s_setprio(0);

        __syncthreads();
        cur ^= 1;
    }

    float ltot = lrun + __shfl_xor(lrun, 32);
    float rl = 1.0f / ltot;
    size_t cb = (size_t)b * 2048 * 1024 + (size_t)(qr0 + l31) * 1024 + (size_t)h * 64;
    #pragma unroll
    for (int r = 0; r < 16; r++) {
        int d = (r & 3) + 8 * (r >> 2) + 4 * half;
        ctx[cb + d]      = f2bf(ot0[r] * rl);
        ctx[cb + 32 + d] = f2bf(ot1[r] * rl);
    }
}

// ---------------- launch ----------------
extern "C" void kernel_launch(void* const* d_in, const int* in_sizes, int n_in,
                              void* d_out, int out_size, void* d_ws, size_t ws_size,
                              hipStream_t stream) {
    const float* x      = (const float*)d_in[0];
    const float* ln1_s  = (const float*)d_in[1];
    const float* ln1_b  = (const float*)d_in[2];
    const float* ln2_s  = (const float*)d_in[3];
    const float* ln2_b  = (const float*)d_in[4];
    const float* qkv_w  = (const float*)d_in[5];
    const float* qkv_b  = (const float*)d_in[6];
    const float* proj_w = (const float*)d_in[7];
    const float* proj_b = (const float*)d_in[8];
    const float* fc1_w  = (const float*)d_in[9];
    const float* fc1_b  = (const float*)d_in[10];
    const float* fc2_w  = (const float*)d_in[11];
    const float* fc2_b  = (const float*)d_in[12];
    float* out = (float*)d_out;

    char* ws = (char*)d_ws;
    unsigned short* vtb  = (unsigned short*)(ws + 0);
    float*          x1   = (float*)(ws + 0);
    unsigned short* h    = (unsigned short*)(ws + (size_t)32 * 1024 * 1024);
    unsigned short* qkvb = (unsigned short*)(ws + (size_t)48 * 1024 * 1024);
    unsigned short* gbuf = (unsigned short*)(ws + (size_t)48 * 1024 * 1024);
    unsigned short* ctxb = (unsigned short*)(ws + (size_t)96 * 1024 * 1024);
    unsigned short* wT   = (unsigned short*)(ws + (size_t)112 * 1024 * 1024);

    dim3 tb(32, 8);

    // 1) qkv_w^T
    transpose_kernel<<<dim3(96, 32), tb, 0, stream>>>(qkv_w, wT, 1024, 3072);
    // 2) h = LN1(x)
    ln_kernel<<<8192, 256, 0, stream>>>(x, ln1_s, ln1_b, h);
    // 3) qkv = h @ qkv_w + b   (+ V^T scatter)   grid 24x32 = 768
    gemm256_kernel<3,128><<<dim3(24, 32), 512, 0, stream>>>(h, wT, qkv_b, nullptr, qkvb, vtb, 8192, 3072, 1024);
    // 4) attention (8-warp 32x32)
    attn_kernel<<<dim3(8, 64), 512, 0, stream>>>(qkvb, vtb, ctxb);
    // 5) proj_w^T
    transpose_kernel<<<dim3(32, 32), tb, 0, stream>>>(proj_w, wT, 1024, 1024);
    // 6) x1 = x + ctx @ proj_w + b   grid 8x32 = 256
    gemm256_kernel<1,128><<<dim3(8, 32), 512, 0, stream>>>(ctxb, wT, proj_b, x, x1, nullptr, 8192, 1024, 1024);
    // 7) h = LN2(x1)
    ln_kernel<<<8192, 256, 0, stream>>>(x1, ln2_s, ln2_b, h);
    // 8) fc1_w^T
    transpose_kernel<<<dim3(128, 32), tb, 0, stream>>>(fc1_w, wT, 1024, 4096);
    // 9) g = gelu(h @ fc1_w + b)   grid 16x32 = 512
    gemm256_kernel<2,256><<<dim3(16, 32), 512, 0, stream>>>(h, wT, fc1_b, nullptr, gbuf, nullptr, 8192, 4096, 1024);
    // 10) fc2_w^T
    transpose_kernel<<<dim3(32, 128), tb, 0, stream>>>(fc2_w, wT, 4096, 1024);
    // 11) out = x1 + g @ fc2_w + b   grid 8x32 = 256
    gemm256_kernel<1,128><<<dim3(8, 32), 512, 0, stream>>>(gbuf, wT, fc2_b, x1, out, nullptr, 8192, 1024, 4096);
}

// Round 7
// 422.652 us; speedup vs baseline: 1.3898x; 1.0097x over previous
//
#include <hip/hip_runtime.h>
#include <hip/hip_bf16.h>

typedef __attribute__((ext_vector_type(4))) float f32x4;
typedef __attribute__((ext_vector_type(16))) float f32x16;
typedef __attribute__((ext_vector_type(8))) short bf16x8;

__device__ __forceinline__ unsigned short f2bf(float f) {
    return __bfloat16_as_ushort(__float2bfloat16(f));
}

typedef __attribute__((address_space(1))) const unsigned char* gas_ptr;
typedef __attribute__((address_space(3))) unsigned char* las_ptr;
__device__ __forceinline__ void gload16(const void* g, void* l) {
    __builtin_amdgcn_global_load_lds((gas_ptr)g, (las_ptr)l, 16, 0, 0);
}

__device__ __forceinline__ unsigned cvt_pk_bf16(float lo, float hi) {
    unsigned r;
    asm("v_cvt_pk_bf16_f32 %0, %1, %2" : "=v"(r) : "v"(lo), "v"(hi));
    return r;
}

// ---------------- LayerNorm: fp32 in -> bf16 out -------------------
__global__ __launch_bounds__(256) void ln_kernel(
    const float* __restrict__ x, const float* __restrict__ scale,
    const float* __restrict__ bias, unsigned short* __restrict__ out)
{
    int row = blockIdx.x;
    const float* xr = x + (size_t)row * 1024;
    int t = threadIdx.x;
    float4 v = ((const float4*)xr)[t];
    float s  = v.x + v.y + v.z + v.w;
    float ss = v.x*v.x + v.y*v.y + v.z*v.z + v.w*v.w;
    #pragma unroll
    for (int m = 32; m; m >>= 1) { s += __shfl_down(s, m); ss += __shfl_down(ss, m); }
    __shared__ float red[8];
    int wid = t >> 6;
    if ((t & 63) == 0) { red[wid*2] = s; red[wid*2+1] = ss; }
    __syncthreads();
    s  = red[0] + red[2] + red[4] + red[6];
    ss = red[1] + red[3] + red[5] + red[7];
    float mu  = s * (1.0f/1024.0f);
    float var = ss * (1.0f/1024.0f) - mu*mu;
    float inv = rsqrtf(var + 1e-6f);
    float4 sc = ((const float4*)scale)[t];
    float4 bi = ((const float4*)bias)[t];
    ushort4 o;
    o.x = f2bf((v.x - mu)*inv*sc.x + bi.x);
    o.y = f2bf((v.y - mu)*inv*sc.y + bi.y);
    o.z = f2bf((v.z - mu)*inv*sc.z + bi.z);
    o.w = f2bf((v.w - mu)*inv*sc.w + bi.w);
    ((ushort4*)(out + (size_t)row * 1024))[t] = o;
}

// ---------------- Weight transpose: fp32 [K][N] -> bf16 [N][K] -----
__global__ __launch_bounds__(256) void transpose_kernel(
    const float* __restrict__ W, unsigned short* __restrict__ Wt, int K, int N)
{
    __shared__ float tile[32][33];
    int n0 = blockIdx.x * 32, k0 = blockIdx.y * 32;
    int tx = threadIdx.x, ty = threadIdx.y;
    #pragma unroll
    for (int j = 0; j < 32; j += 8)
        tile[ty + j][tx] = W[(size_t)(k0 + ty + j) * N + n0 + tx];
    __syncthreads();
    #pragma unroll
    for (int j = 0; j < 32; j += 8)
        Wt[(size_t)(n0 + ty + j) * K + k0 + tx] = f2bf(tile[tx][ty + j]);
}

// ------- GEMM 256xBN tile, swizzled LDS, raw-barrier dbuf ---------
template<int EPI, int BN>
__global__ __launch_bounds__(512, 2) void gemm256_kernel(
    const unsigned short* __restrict__ A,
    const unsigned short* __restrict__ Bt,
    const float* __restrict__ bias,
    const float* __restrict__ res,
    void* __restrict__ out,
    unsigned short* __restrict__ vtout,
    int M, int N, int K)
{
    constexpr int BM = 256;
    constexpr int WARPS_N = (BN == 256) ? 4 : 2;
    constexpr int WM = (BN == 256) ? 128 : 64;
    constexpr int WN = 64;
    constexpr int MQ = WM / 64;
    constexpr int NF = WN / 16;
    constexpr int NB = BN / 64;

    __shared__ __align__(16) unsigned short Al[2][BM * 64];
    __shared__ __align__(16) unsigned short Bl[2][BN * 64];

    int t = threadIdx.x;
    int wid = t >> 6, lane = t & 63;
    int wr = wid / WARPS_N, wc = wid % WARPS_N;
    int l15 = lane & 15, lg = lane >> 4;

    int gx = gridDim.x;
    int nwg = gx * gridDim.y;
    int orig = blockIdx.y * gx + blockIdx.x;
    int cpx = nwg >> 3;
    int wg = (orig & 7) * cpx + (orig >> 3);
    int bx = wg % gx, by = wg / gx;
    int brow = by * BM, bcol = bx * BN;

    f32x4 acc[MQ * 4][NF] = {};

    int sr  = t >> 3;
    int scb = (t & 7) * 16;
    int sce = (scb ^ ((sr & 7) << 4)) >> 1;
    const size_t aoff = (size_t)(brow + sr) * K + sce;
    const size_t boff = (size_t)(bcol + sr) * K + sce;

    auto stage = [&](int b, int kt2) {
        int k0 = kt2 << 6;
        char* la = (char*)Al[b] + (wid << 10);
        char* lb = (char*)Bl[b] + (wid << 10);
        #pragma unroll
        for (int i = 0; i < 4; i++)
            gload16(A + aoff + (size_t)(i * 64) * K + k0, la + i * 8192);
        #pragma unroll
        for (int j = 0; j < NB; j++)
            gload16(Bt + boff + (size_t)(j * 64) * K + k0, lb + j * 8192);
    };

    stage(0, 0);
    asm volatile("s_waitcnt vmcnt(0)" ::: "memory");
    __builtin_amdgcn_s_barrier();

    int nk = K >> 6;
    int rsw = (l15 & 7) << 4;
    for (int kt = 0; kt < nk; kt++) {
        int cur = kt & 1;
        if (kt + 1 < nk) stage(cur ^ 1, kt + 1);

        const char* Ab = (const char*)Al[cur];
        const char* Bb = (const char*)Bl[cur];

        bf16x8 bfr[NF][2];
        #pragma unroll
        for (int nf = 0; nf < NF; nf++) {
            int rb = wc * WN + nf * 16 + l15;
            #pragma unroll
            for (int kk = 0; kk < 2; kk++)
                bfr[nf][kk] = *(const bf16x8*)(Bb + rb * 128 + ((kk * 64 + lg * 16) ^ rsw));
        }
        #pragma unroll
        for (int mq = 0; mq < MQ; mq++) {
            bf16x8 af[4][2];
            #pragma unroll
            for (int mf = 0; mf < 4; mf++) {
                int ra = wr * WM + mq * 64 + mf * 16 + l15;
                #pragma unroll
                for (int kk = 0; kk < 2; kk++)
                    af[mf][kk] = *(const bf16x8*)(Ab + ra * 128 + ((kk * 64 + lg * 16) ^ rsw));
            }
            __builtin_amdgcn_s_setprio(1);
            #pragma unroll
            for (int mf = 0; mf < 4; mf++)
                #pragma unroll
                for (int nf = 0; nf < NF; nf++)
                    #pragma unroll
                    for (int kk = 0; kk < 2; kk++)
                        acc[mq*4+mf][nf] = __builtin_amdgcn_mfma_f32_16x16x32_bf16(
                            af[mf][kk], bfr[nf][kk], acc[mq*4+mf][nf], 0, 0, 0);
            __builtin_amdgcn_s_setprio(0);
        }

        asm volatile("s_waitcnt vmcnt(0)" ::: "memory");
        __builtin_amdgcn_s_barrier();
    }

    #pragma unroll
    for (int mi = 0; mi < MQ * 4; mi++) {
        #pragma unroll
        for (int nf = 0; nf < NF; nf++) {
            int col = bcol + wc * WN + nf * 16 + l15;
            float bs = bias[col];
            #pragma unroll
            for (int r = 0; r < 4; r++) {
                int row = brow + wr * WM + mi * 16 + lg * 4 + r;
                size_t idx = (size_t)row * N + col;
                float v = acc[mi][nf][r] + bs;
                if (EPI == 1) {
                    ((float*)out)[idx] = v + res[idx];
                } else if (EPI == 2) {
                    float u = v + 0.044715f * v * v * v;
                    float e = __builtin_amdgcn_exp2f(-2.3022077f * u);
                    float g = v * __builtin_amdgcn_rcpf(1.0f + e);
                    ((unsigned short*)out)[idx] = f2bf(g);
                } else {
                    unsigned short bv = f2bf(v);
                    ((unsigned short*)out)[idx] = bv;
                    if (col >= 2048) {
                        int hd = col - 2048;
                        int b = row >> 11, s = row & 2047;
                        vtout[((size_t)((b << 4) + (hd >> 6)) * 64 + (hd & 63)) * 2048 + s] = bv;
                    }
                }
            }
        }
    }
}

// ---------------- Flash attention (8-warp, 32x32 swapped, pi-PV) ----
// S^T = K.Q^T; each lane owns q=lane&31. PV uses per-MFMA key permutation
// pi so the P B-frags are the raw cvt_pk words (no cross-half exchange):
//   k-slot half*8+j  ->  key ks*16 + {0-3,8-11}+4*half  (j<4: first group)
// V^T A-frags read the matching keys via 2x ds_read_b64 per row.
__global__ __launch_bounds__(512, 2) void attn_kernel(
    const unsigned short* __restrict__ qkv, const unsigned short* __restrict__ vt,
    unsigned short* __restrict__ ctx)
{
    __shared__ unsigned short Kl[2][4096];   // [64 keys][64 d], XOR-swizzled rows
    __shared__ unsigned short Vl[2][4096];   // [64 d][64 keys], XOR-swizzled rows

    int t = threadIdx.x;
    int wid = t >> 6, lane = t & 63;
    int l31 = lane & 31, half = lane >> 5;
    int bh = blockIdx.y;
    int b = bh >> 4, h = bh & 15;
    int qr0 = blockIdx.x * 256 + wid * 32;

    const size_t qbase = (size_t)b * 2048 * 3072 + (size_t)h * 64;
    const unsigned short* vbase = vt + (size_t)bh * 64 * 2048;

    bf16x8 qf[4];
    #pragma unroll
    for (int ds = 0; ds < 4; ds++)
        qf[ds] = *(const bf16x8*)(qkv + qbase + (size_t)(qr0 + l31) * 3072 + ds*16 + half*8);

    f32x16 ot0 = {}, ot1 = {};
    float mrun = -1e30f, lrun = 0.0f;
    const float C = 0.125f * 1.44269504f;

    int srow = t >> 3;
    int ssw = ((t & 7) * 16) ^ ((srow & 7) << 4);
    const unsigned short* kg = qkv + qbase + 1024 + (size_t)srow * 3072 + (ssw >> 1);
    const unsigned short* vg = vbase + (size_t)srow * 2048 + (ssw >> 1);

    gload16(kg, (char*)Kl[0] + t * 16);
    gload16(vg, (char*)Vl[0] + t * 16);
    __syncthreads();

    int cur = 0;
    for (int kt = 0; kt < 32; kt++) {
        if (kt < 31) {
            gload16(kg + (size_t)(kt + 1) * 64 * 3072, (char*)Kl[cur ^ 1] + t * 16);
            gload16(vg + (kt + 1) * 64,               (char*)Vl[cur ^ 1] + t * 16);
        }

        const char* Kb = (const char*)Kl[cur];
        const char* Vb = (const char*)Vl[cur];
        int sw = (l31 & 7) << 4;

        // S^T = K . Q^T
        f32x16 st0 = {}, st1 = {};
        __builtin_amdgcn_s_setprio(1);
        #pragma unroll
        for (int ds = 0; ds < 4; ds++) {
            int colb = ds*32 + half*16;
            bf16x8 k0 = *(const bf16x8*)(Kb + l31*128 + (colb ^ sw));
            bf16x8 k1 = *(const bf16x8*)(Kb + (32 + l31)*128 + (colb ^ sw));
            st0 = __builtin_amdgcn_mfma_f32_32x32x16_bf16(k0, qf[ds], st0, 0, 0, 0);
            st1 = __builtin_amdgcn_mfma_f32_32x32x16_bf16(k1, qf[ds], st1, 0, 0, 0);
        }
        __builtin_amdgcn_s_setprio(0);

        // row max over own 32 keys, then lane-pair exchange
        float mx = fmaxf(st0[0], st0[1]);
        #pragma unroll
        for (int r = 2; r < 16; r++) mx = fmaxf(mx, st0[r]);
        #pragma unroll
        for (int r = 0; r < 16; r++) mx = fmaxf(mx, st1[r]);
        mx = fmaxf(mx, __shfl_xor(mx, 32));
        float pm = mx * C;

        // defer-max (THR = 8/ln2)
        bool grow = pm > mrun + 11.5416f;
        if (__any(grow)) {
            float mn = fmaxf(mrun, pm);
            float corr = __builtin_amdgcn_exp2f(mrun - mn);
            mrun = mn;
            lrun *= corr;
            ot0 *= corr;
            ot1 *= corr;
        }

        // P = exp2(S*C - mrun); pack to bf16 words (order = C/D reg order)
        unsigned w0[8], w1[8];
        float sum = 0.0f;
        {
            float e[16];
            #pragma unroll
            for (int r = 0; r < 16; r++) { e[r] = __builtin_amdgcn_exp2f(fmaf(st0[r], C, -mrun)); sum += e[r]; }
            #pragma unroll
            for (int p = 0; p < 8; p++) w0[p] = cvt_pk_bf16(e[2*p], e[2*p+1]);
            #pragma unroll
            for (int r = 0; r < 16; r++) { e[r] = __builtin_amdgcn_exp2f(fmaf(st1[r], C, -mrun)); sum += e[r]; }
            #pragma unroll
            for (int p = 0; p < 8; p++) w1[p] = cvt_pk_bf16(e[2*p], e[2*p+1]);
        }
        lrun += sum;

        // O^T += V^T . P^T with per-MFMA key permutation pi:
        // MFMA ks consumes keys ks*16 + pi, pi(half*8+j) = {0-3,8-11}+4*half.
        // B-frag = w[ks&1 ? 4..7 : 0..3] of (ks<2 ? w0 : w1) directly.
        // A-frag rows d=l31 / 32+l31: keys at byte offs ks*32+half*8 and +16.
        __builtin_amdgcn_s_setprio(1);
        #pragma unroll
        for (int ks = 0; ks < 4; ks++) {
            union { unsigned u[4]; bf16x8 v; } pf;
            unsigned* w = (ks < 2) ? w0 : w1;
            int o4 = (ks & 1) * 4;
            pf.u[0] = w[o4 + 0]; pf.u[1] = w[o4 + 1]; pf.u[2] = w[o4 + 2]; pf.u[3] = w[o4 + 3];
            int lo = ks*32 + half*8;
            union { unsigned long long d[2]; bf16x8 v; } va, vb;
            va.d[0] = *(const unsigned long long*)(Vb + l31*128 + (lo ^ sw));
            va.d[1] = *(const unsigned long long*)(Vb + l31*128 + ((lo + 16) ^ sw));
            vb.d[0] = *(const unsigned long long*)(Vb + (32 + l31)*128 + (lo ^ sw));
            vb.d[1] = *(const unsigned long long*)(Vb + (32 + l31)*128 + ((lo + 16) ^ sw));
            ot0 = __builtin_amdgcn_mfma_f32_32x32x16_bf16(va.v, pf.v, ot0, 0, 0, 0);
            ot1 = __builtin_amdgcn_mfma_f32_32x32x16_bf16(vb.v, pf.v, ot1, 0, 0, 0);
        }
        __builtin_amdgcn_s_setprio(0);

        __syncthreads();
        cur ^= 1;
    }

    float ltot = lrun + __shfl_xor(lrun, 32);
    float rl = 1.0f / ltot;
    size_t cb = (size_t)b * 2048 * 1024 + (size_t)(qr0 + l31) * 1024 + (size_t)h * 64;
    #pragma unroll
    for (int r = 0; r < 16; r++) {
        int d = (r & 3) + 8 * (r >> 2) + 4 * half;
        ctx[cb + d]      = f2bf(ot0[r] * rl);
        ctx[cb + 32 + d] = f2bf(ot1[r] * rl);
    }
}

// ---------------- launch ----------------
extern "C" void kernel_launch(void* const* d_in, const int* in_sizes, int n_in,
                              void* d_out, int out_size, void* d_ws, size_t ws_size,
                              hipStream_t stream) {
    const float* x      = (const float*)d_in[0];
    const float* ln1_s  = (const float*)d_in[1];
    const float* ln1_b  = (const float*)d_in[2];
    const float* ln2_s  = (const float*)d_in[3];
    const float* ln2_b  = (const float*)d_in[4];
    const float* qkv_w  = (const float*)d_in[5];
    const float* qkv_b  = (const float*)d_in[6];
    const float* proj_w = (const float*)d_in[7];
    const float* proj_b = (const float*)d_in[8];
    const float* fc1_w  = (const float*)d_in[9];
    const float* fc1_b  = (const float*)d_in[10];
    const float* fc2_w  = (const float*)d_in[11];
    const float* fc2_b  = (const float*)d_in[12];
    float* out = (float*)d_out;

    char* ws = (char*)d_ws;
    unsigned short* vtb  = (unsigned short*)(ws + 0);
    float*          x1   = (float*)(ws + 0);
    unsigned short* h    = (unsigned short*)(ws + (size_t)32 * 1024 * 1024);
    unsigned short* qkvb = (unsigned short*)(ws + (size_t)48 * 1024 * 1024);
    unsigned short* gbuf = (unsigned short*)(ws + (size_t)48 * 1024 * 1024);
    unsigned short* ctxb = (unsigned short*)(ws + (size_t)96 * 1024 * 1024);
    unsigned short* wT   = (unsigned short*)(ws + (size_t)112 * 1024 * 1024);

    dim3 tb(32, 8);

    // 1) qkv_w^T
    transpose_kernel<<<dim3(96, 32), tb, 0, stream>>>(qkv_w, wT, 1024, 3072);
    // 2) h = LN1(x)
    ln_kernel<<<8192, 256, 0, stream>>>(x, ln1_s, ln1_b, h);
    // 3) qkv = h @ qkv_w + b   (+ V^T scatter)   grid 24x32 = 768
    gemm256_kernel<3,128><<<dim3(24, 32), 512, 0, stream>>>(h, wT, qkv_b, nullptr, qkvb, vtb, 8192, 3072, 1024);
    // 4) attention (8-warp 32x32)
    attn_kernel<<<dim3(8, 64), 512, 0, stream>>>(qkvb, vtb, ctxb);
    // 5) proj_w^T
    transpose_kernel<<<dim3(32, 32), tb, 0, stream>>>(proj_w, wT, 1024, 1024);
    // 6) x1 = x + ctx @ proj_w + b   grid 8x32 = 256
    gemm256_kernel<1,128><<<dim3(8, 32), 512, 0, stream>>>(ctxb, wT, proj_b, x, x1, nullptr, 8192, 1024, 1024);
    // 7) h = LN2(x1)
    ln_kernel<<<8192, 256, 0, stream>>>(x1, ln2_s, ln2_b, h);
    // 8) fc1_w^T
    transpose_kernel<<<dim3(128, 32), tb, 0, stream>>>(fc1_w, wT, 1024, 4096);
    // 9) g = gelu(h @ fc1_w + b)   grid 16x32 = 512
    gemm256_kernel<2,256><<<dim3(16, 32), 512, 0, stream>>>(h, wT, fc1_b, nullptr, gbuf, nullptr, 8192, 4096, 1024);
    // 10) fc2_w^T
    transpose_kernel<<<dim3(32, 128), tb, 0, stream>>>(fc2_w, wT, 4096, 1024);
    // 11) out = x1 + g @ fc2_w + b   grid 8x32 = 256
    gemm256_kernel<1,128><<<dim3(8, 32), 512, 0, stream>>>(gbuf, wT, fc2_b, x1, out, nullptr, 8192, 1024, 4096);
}